// Round 7
// baseline (447.740 us; speedup 1.0000x reference)
//
#include <hip/hip_runtime.h>

typedef unsigned short u16;
typedef unsigned char  u8;
typedef unsigned int   u32;
typedef unsigned long long u64;
typedef __bf16 bf16x8 __attribute__((ext_vector_type(8)));
typedef float  f32x4  __attribute__((ext_vector_type(4)));
typedef u16    u16x8  __attribute__((ext_vector_type(8)));
typedef u16    u16x4  __attribute__((ext_vector_type(4)));

// ---------------- constants ----------------
#define R_TOTAL 327360
#define LAB_OFF 3273600   // 2*R*5
#define MAT_OFF 3928320   // LAB_OFF + 2*R
#define NLBLK   1279      // label blocks per image (1279*256 >= R_TOTAL)

static __device__ const int    D_LOG2G[5] = {7, 6, 5, 4, 3};
static __device__ const size_t D_FTOFF[5] = {0, 8389120, 10486784, 11011584, 11143168};
static __device__ const int    D_TPOFF[5] = {0, 32768, 40960, 43008, 43520}; // pos units (x256 ch)
static __device__ const int    D_AOFF[5]  = {0, 245760, 307200, 322560, 326400};

static __device__ const float D_WH[15][2] = {
  {22.627416997969522f, 45.254833995939045f}, {32.f, 32.f},   {45.254833995939045f, 22.627416997969522f},
  {45.254833995939045f, 90.50966799187809f},  {64.f, 64.f},   {90.50966799187809f, 45.254833995939045f},
  {90.50966799187809f, 181.01933598375618f},  {128.f, 128.f}, {181.01933598375618f, 90.50966799187809f},
  {181.01933598375618f, 362.03867196751236f}, {256.f, 256.f}, {362.03867196751236f, 181.01933598375618f},
  {362.03867196751236f, 724.0773439350247f},  {512.f, 512.f}, {724.0773439350247f, 362.03867196751236f},
};

__device__ __forceinline__ u16 f2bf(float x) {          // RNE f32->bf16
  u32 u = __float_as_uint(x);
  u32 r = u + 0x7FFFu + ((u >> 16) & 1u);
  return (u16)(r >> 16);
}

__device__ __forceinline__ void glds16(const void* g, void* l) {
  __builtin_amdgcn_global_load_lds(
      (const __attribute__((address_space(1))) u32*)g,
      (__attribute__((address_space(3))) u32*)l, 16, 0, 0);
}

// ---------------- anchor decode (contract OFF) ----------------
__device__ inline void anchor_box(int r, float& x1, float& y1, float& x2, float& y2) {
  #pragma clang fp contract(off)
  int off, lg;
  if (r < 245760)      { off = 0;      lg = 7; }
  else if (r < 307200) { off = 245760; lg = 6; }
  else if (r < 322560) { off = 307200; lg = 5; }
  else if (r < 326400) { off = 322560; lg = 4; }
  else                 { off = 326400; lg = 3; }
  int rem  = r - off;
  int a    = rem >> (2 * lg);
  int rem2 = rem & ((1 << (2 * lg)) - 1);
  int i = rem2 >> lg;
  int j = rem2 & ((1 << lg) - 1);
  float stride = (float)(512 >> lg);
  float cx = (float)i * stride;
  float cy = (float)j * stride;
  float hw = D_WH[a][0] * 0.5f;
  float hh = D_WH[a][1] * 0.5f;
  x1 = cx - hw; y1 = cy - hh; x2 = cx + hw; y2 = cy + hh;
}

__device__ inline float iou_f(float ax1, float ay1, float ax2, float ay2,
                              float bx1, float by1, float bx2, float by2) {
  #pragma clang fp contract(off)
  float ltx = fmaxf(ax1, bx1), lty = fmaxf(ay1, by1);
  float rbx = fminf(ax2, bx2), rby = fminf(ay2, by2);
  float iw = fmaxf(rbx - ltx, 0.f);
  float ih = fmaxf(rby - lty, 0.f);
  float inter = iw * ih;
  float aa = (ax2 - ax1) * (ay2 - ay1);
  float ab = (bx2 - bx1) * (by2 - by1);
  return inter / (aa + ab - inter);
}

// ---------------- K1: packs + feature transpose + labels/argmax (fused) ------------
// bid < 2304   : conv_w -> bf16 [ks][co][32] quarter-swizzled
// bid < 2384   : head weights -> Wb bf16 [80][256] + bias[80]
// bid < 3076   : features [b][ci][p] f32 -> [b][p][ci] bf16 (+zero halo row)
// else (2558)  : labels + matched + per-gt atomicMax argmax + last-block finalize
__global__ __launch_bounds__(256) void prep_label_kernel(
    const float* __restrict__ cw, u16* __restrict__ wp,
    const float* __restrict__ cls_w, const float* __restrict__ cls_b,
    const float* __restrict__ box_w, const float* __restrict__ box_b,
    u16* __restrict__ Wb, float* __restrict__ hbias,
    const float* __restrict__ f0, const float* __restrict__ f1,
    const float* __restrict__ f2, const float* __restrict__ f3,
    const float* __restrict__ f4, u16* __restrict__ Ft,
    const float* __restrict__ gt, float* __restrict__ out,
    u64* __restrict__ win, u32* __restrict__ done) {
  __shared__ union {
    float tile[64][65];
    struct {
      float gx[32][4];
      float sh[256][33];
      float2 red[32][8];
    } L;
  } sm;
  __shared__ int lastFlag;
  const int tid = threadIdx.x;
  if (blockIdx.x < 2304) {
    int idx = blockIdx.x * 256 + tid;   // < 589824
    int ks  = idx >> 13;
    int rem = idx & 8191;
    int co  = rem >> 5;
    int k   = rem & 31;
    int tap = ks >> 3;
    int cb  = ks & 7;
    float v = cw[co * 2304 + (cb * 32 + k) * 9 + tap];
    int qd = k >> 3, wi = k & 7;
    int dq = qd ^ ((co >> 1) & 3);
    wp[(size_t)ks * 8192 + co * 32 + dq * 8 + wi] = f2bf(v);
    return;
  }
  if (blockIdx.x < 2384) {
    int idx = (blockIdx.x - 2304) * 256 + tid;   // < 20480
    int row = idx >> 8, k = idx & 255;
    float v = (row < 15) ? cls_w[row * 256 + k] : (row < 75) ? box_w[(row - 15) * 256 + k] : 0.f;
    Wb[row * 256 + k] = f2bf(v);
    if (idx < 80) hbias[idx] = (idx < 15) ? cls_b[idx] : (idx < 75) ? box_b[idx - 15] : 0.f;
    return;
  }
  if (blockIdx.x < 3076) {
    int bid = blockIdx.x - 2384;    // < 692
    int l, base, nb1;
    if (bid < 514)      { l = 0; base = 0;   nb1 = 257; }
    else if (bid < 644) { l = 1; base = 514; nb1 = 65; }
    else if (bid < 678) { l = 2; base = 644; nb1 = 17; }
    else if (bid < 688) { l = 3; base = 678; nb1 = 5; }
    else                { l = 4; base = 688; nb1 = 2; }
    const int lg = D_LOG2G[l];
    const int HW = 1 << (2 * lg);
    int blk = bid - base;
    int b   = blk / nb1;
    int p0  = (blk - b * nb1) * 64;
    u16* dst = Ft + D_FTOFF[l];
    if (p0 >= HW) {      // zero halo row
      if (tid < 32) {
        u16x8 z = (u16x8)0;
        *(u16x8*)(dst + ((size_t)b * (HW + 1) + HW) * 256 + tid * 8) = z;
      }
      return;
    }
    const float* fsel = (l == 0) ? f0 : (l == 1) ? f1 : (l == 2) ? f2 : (l == 3) ? f3 : f4;
    const float* fb = fsel + (size_t)b * 256 * HW;
    for (int cg = 0; cg < 4; ++cg) {
      __syncthreads();
      #pragma unroll
      for (int i = 0; i < 16; ++i) {
        int idx = i * 256 + tid;
        int cl = idx >> 6, pp = idx & 63;
        sm.tile[cl][pp] = fb[(size_t)(cg * 64 + cl) * HW + p0 + pp];
      }
      __syncthreads();
      #pragma unroll
      for (int i = 0; i < 2; ++i) {
        int slot = i * 256 + tid;
        int pos = slot >> 3, ch = slot & 7;
        u16x8 v;
        #pragma unroll
        for (int j = 0; j < 8; ++j) v[j] = f2bf(sm.tile[ch * 8 + j][pos]);
        *(u16x8*)(dst + ((size_t)b * (HW + 1) + p0 + pos) * 256 + cg * 64 + ch * 8) = v;
      }
    }
    return;
  }
  // ---------------- label path ----------------
  {
    #pragma clang fp contract(off)
    const int lb = blockIdx.x - 3076;          // < 2558
    const int b = (lb >= NLBLK) ? 1 : 0;
    const int lblk = lb - b * NLBLK;
    if (tid < 32) {
      const float* gp = gt + ((size_t)b * 32 + tid) * 4;
      float x = gp[0], y = gp[1], w = gp[2], h = gp[3];
      sm.L.gx[tid][0] = x; sm.L.gx[tid][1] = y;
      sm.L.gx[tid][2] = x + w; sm.L.gx[tid][3] = y + h;
    }
    __syncthreads();
    const int r = lblk * 256 + tid;
    const bool valid = (r < R_TOTAL);
    const int rv = valid ? r : 0;
    float ax1, ay1, ax2, ay2;
    anchor_box(rv, ax1, ay1, ax2, ay2);
    float best = -1e30f; int bi = 0;
    for (int n = 0; n < 32; ++n) {
      float v = iou_f(ax1, ay1, ax2, ay2, sm.L.gx[n][0], sm.L.gx[n][1], sm.L.gx[n][2], sm.L.gx[n][3]);
      sm.L.sh[tid][n] = valid ? v : -1e30f;
      if (v > best) { best = v; bi = n; }    // first-max (matches jnp.argmax)
    }
    if (valid) {
      float lab = (best < 0.3f) ? 0.f : ((best > 0.7f) ? 1.f : -1.f);
      out[LAB_OFF + (size_t)b * R_TOTAL + r] = lab;
      float4 m; m.x = sm.L.gx[bi][0]; m.y = sm.L.gx[bi][1];
      m.z = sm.L.gx[bi][2]; m.w = sm.L.gx[bi][3];
      *(float4*)&out[MAT_OFF + ((size_t)b * R_TOTAL + r) * 4] = m;
    }
    __syncthreads();
    // per-gt max over this block's 256 anchors
    const int n = tid & 31, gr = tid >> 5;
    float bv = -1e30f; int li = 0;
    #pragma unroll 4
    for (int a = 0; a < 32; ++a) {
      int la = gr * 32 + a;
      float v = sm.L.sh[la][n];
      if (v > bv) { bv = v; li = la; }       // ascending scan keeps first-max
    }
    sm.L.red[n][gr] = make_float2(bv, __int_as_float(li));
    __syncthreads();
    if (tid < 32) {
      float fv = -1e30f; int fi = 0;
      #pragma unroll
      for (int g2 = 0; g2 < 8; ++g2) {
        float2 pv = sm.L.red[tid][g2];
        int ii = __float_as_int(pv.y);
        if (pv.x > fv) { fv = pv.x; fi = ii; }   // g2 ascending => idx ascending
      }
      // key: iou bits (>=0 so unsigned-monotone) in high32, ~global_idx low32
      u64 key = ((u64)__float_as_uint(fv) << 32) |
                (u64)(0xFFFFFFFFu - (u32)(lblk * 256 + fi));
      atomicMax(&win[b * 32 + tid], key);
    }
    __threadfence();
    __syncthreads();
    if (tid == 0) {
      u32 old = atomicAdd(&done[b], 1u);
      lastFlag = (old == NLBLK - 1) ? 1 : 0;
    }
    __syncthreads();
    if (lastFlag && tid < 32) {
      u64 k = atomicMax(&win[b * 32 + tid], 0ull);   // device-scope read
      u32 hi = (u32)(k >> 32);
      int ra = hi ? (int)(0xFFFFFFFFu - (u32)k) : 0;
      float x1, y1, x2, y2;
      anchor_box(ra, x1, y1, x2, y2);
      float score = -1e30f;
      for (int n2 = 0; n2 < 32; ++n2) {
        float v = iou_f(x1, y1, x2, y2, sm.L.gx[n2][0], sm.L.gx[n2][1],
                        sm.L.gx[n2][2], sm.L.gx[n2][3]);
        score = fmaxf(score, v);
      }
      out[LAB_OFF + (size_t)b * R_TOTAL + ra] = (score < 0.3f) ? 0.f : 1.f;
    }
  }
}

// ---------------- K2: 3x3 conv via bf16 MFMA ---------------------------------------
// R4 grid (1364 blocks, BM=128 co x BN=64 pos, BK=32) but 256 thr / 4 waves
// (2co x 2pos wave grid, wave tile 64x32) for 2x TLP. 2-phase double-buffer.
__global__ __launch_bounds__(256) void conv_mfma_kernel(
    const u16* __restrict__ Ft, const u16* __restrict__ wp,
    const float* __restrict__ cb, u16* __restrict__ tP) {
  __shared__ __align__(16) u8 Asb[16384];   // 2 x 8KB (128 co x 32 ch)
  __shared__ __align__(16) u8 Bsb[8192];    // 2 x 4KB (64 pos x 32 ch)
  const int bid = blockIdx.x;
  int l, base;
  if (bid < 1024)      { l = 0; base = 0; }
  else if (bid < 1280) { l = 1; base = 1024; }
  else if (bid < 1344) { l = 2; base = 1280; }
  else if (bid < 1360) { l = 3; base = 1344; }
  else                 { l = 4; base = 1360; }
  const int lg = D_LOG2G[l];
  const int g = 1 << lg, HW = 1 << (2 * lg);
  const int lognt = 2 * lg - 5;            // log2(64-pos tiles over both images)
  const int blk = bid - base;
  const int ct = blk >> lognt;             // co half
  const int tile = blk & ((1 << lognt) - 1);
  const int n0 = tile << 6;                // flattened pos (tiles never cross images)
  const int co0 = ct << 7;
  const int tid = threadIdx.x;
  const int wv = tid >> 6, lane = tid & 63;
  const int wr = wv >> 1, wc = wv & 1;     // 2x2 wave grid (co x pos)
  const u16* FtL = Ft + D_FTOFF[l];
  const u8* wpb = (const u8*)wp;
  const int b_img = n0 >> (2 * lg);
  // staging: thread covers B row rB (pos n0+rB), quarter dq
  const int dq = tid & 3;
  const int rB = tid >> 2;                 // 0..63
  const int pgb = (n0 + rB) & (HW - 1);
  const int h0 = pgb >> lg, w0 = pgb & (g - 1);
  const int q0 = dq ^ ((rB >> 1) & 3);
  const u16* bimg = FtL + (size_t)b_img * (HW + 1) * 256;
  // fragment LDS byte offsets
  const int lm = lane & 15, lq = lane >> 4;
  int aoffs[4], boffs[2];
  #pragma unroll
  for (int mi = 0; mi < 4; ++mi) {
    int row = wr * 64 + mi * 16 + lm;
    aoffs[mi] = row * 64 + ((lq ^ ((row >> 1) & 3)) << 4);
  }
  #pragma unroll
  for (int ni = 0; ni < 2; ++ni) {
    int col = wc * 32 + ni * 16 + lm;
    boffs[ni] = col * 64 + ((lq ^ ((col >> 1) & 3)) << 4);
  }
  f32x4 acc[4][2];
  #pragma unroll
  for (int mi = 0; mi < 4; ++mi)
    #pragma unroll
    for (int ni = 0; ni < 2; ++ni) acc[mi][ni] = (f32x4)0.f;

  auto tap_src = [&](int tap) -> const u16* {
    const int dh = tap / 3 - 1, dw = tap % 3 - 1;
    int sh = h0 + dh, sw = w0 + dw;
    int rr = ((unsigned)sh < (unsigned)g && (unsigned)sw < (unsigned)g) ? (sh * g + sw) : HW;
    return bimg + (size_t)rr * 256 + q0 * 8;
  };
  auto STAGE = [&](int p, int ks, int cb8, const u16* s0) {
    glds16(s0 + cb8 * 32, Bsb + p * 4096 + wv * 1024);
    const u8* aK = wpb + (size_t)ks * 16384 + co0 * 64;
    glds16(aK + wv * 1024 + lane * 16,       Asb + p * 8192 + wv * 1024);
    glds16(aK + (4 + wv) * 1024 + lane * 16, Asb + p * 8192 + (4 + wv) * 1024);
  };

  const u16* cs0 = tap_src(0);
  int p = 0;
  STAGE(0, 0, 0, cs0);
  __syncthreads();

  for (int tap = 0; tap < 9; ++tap) {
    const u16* ns0 = (tap < 8) ? tap_src(tap + 1) : cs0;
    #pragma unroll
    for (int cb8 = 0; cb8 < 8; ++cb8) {
      if (!(tap == 8 && cb8 == 7)) {
        if (cb8 < 7) STAGE(p ^ 1, tap * 8 + cb8 + 1, cb8 + 1, cs0);
        else         STAGE(p ^ 1, (tap + 1) * 8, 0, ns0);
      }
      bf16x8 af[4], bfr[2];
      #pragma unroll
      for (int mi = 0; mi < 4; ++mi) af[mi] = *(const bf16x8*)(Asb + p * 8192 + aoffs[mi]);
      #pragma unroll
      for (int ni = 0; ni < 2; ++ni) bfr[ni] = *(const bf16x8*)(Bsb + p * 4096 + boffs[ni]);
      #pragma unroll
      for (int mi = 0; mi < 4; ++mi)
        #pragma unroll
        for (int ni = 0; ni < 2; ++ni)
          acc[mi][ni] = __builtin_amdgcn_mfma_f32_16x16x32_bf16(af[mi], bfr[ni], acc[mi][ni], 0, 0, 0);
      __syncthreads();
      p ^= 1;
    }
    cs0 = ns0;
  }
  // epilogue: bias + relu + bf16 store, position-major [p][co]
  u16* tPL = tP + ((size_t)D_TPOFF[l] + (size_t)b_img * HW) * 256;
  #pragma unroll
  for (int mi = 0; mi < 4; ++mi) {
    const int cob = co0 + wr * 64 + mi * 16 + lq * 4;
    const float4 bs = *(const float4*)&cb[cob];
    #pragma unroll
    for (int ni = 0; ni < 2; ++ni) {
      int pp = (n0 + wc * 32 + ni * 16 + lm) & (HW - 1);
      u16x4 v;
      v[0] = f2bf(fmaxf(acc[mi][ni][0] + bs.x, 0.f));
      v[1] = f2bf(fmaxf(acc[mi][ni][1] + bs.y, 0.f));
      v[2] = f2bf(fmaxf(acc[mi][ni][2] + bs.z, 0.f));
      v[3] = f2bf(fmaxf(acc[mi][ni][3] + bs.w, 0.f));
      *(u16x4*)&tPL[(size_t)pp * 256 + cob] = v;
    }
  }
}

// ---------------- K3: 1x1 heads via MFMA  (BM=80, BN=64, K=256) --------------------
__global__ __launch_bounds__(128) void head_mfma_kernel(
    const u16* __restrict__ tP, const u16* __restrict__ Wb,
    const float* __restrict__ hbias, float* __restrict__ out) {
  __shared__ __align__(16) u8 Bsb[32768];
  const int bid = blockIdx.x;
  int l, base;
  if (bid < 512)      { l = 0; base = 0; }
  else if (bid < 640) { l = 1; base = 512; }
  else if (bid < 672) { l = 2; base = 640; }
  else if (bid < 680) { l = 3; base = 672; }
  else                { l = 4; base = 680; }
  const int lg = D_LOG2G[l];
  const int HW = 1 << (2 * lg);
  const int blk = bid - base;
  const int n0 = blk << 6;             // global pos (2 images flattened)
  const int tid = threadIdx.x;
  const int wv = tid >> 6, lane = tid & 63;
  const int lm = lane & 15, lq = lane >> 4;
  const u16* src = tP + ((size_t)D_TPOFF[l] + n0) * 256;
  #pragma unroll
  for (int i = 0; i < 16; ++i) {
    int c = wv + i * 2;
    int slot = c * 64 + lane;
    int pos = slot >> 5, sp = slot & 31;
    glds16(src + (size_t)pos * 256 + ((sp ^ (pos & 7)) << 3), Bsb + c * 1024);
  }
  __syncthreads();
  f32x4 acc[5][2];
  #pragma unroll
  for (int mi = 0; mi < 5; ++mi) { acc[mi][0] = (f32x4)0.f; acc[mi][1] = (f32x4)0.f; }
  for (int kb = 0; kb < 8; ++kb) {
    bf16x8 af[5], bfr[2];
    #pragma unroll
    for (int mi = 0; mi < 5; ++mi)
      af[mi] = *(const bf16x8*)&Wb[(mi * 16 + lm) * 256 + kb * 32 + lq * 8];
    #pragma unroll
    for (int ni = 0; ni < 2; ++ni) {
      int p_ = wv * 32 + ni * 16 + lm;
      bfr[ni] = *(const bf16x8*)(Bsb + p_ * 512 + (((kb * 4 + lq) ^ (p_ & 7)) << 4));
    }
    #pragma unroll
    for (int mi = 0; mi < 5; ++mi)
      #pragma unroll
      for (int ni = 0; ni < 2; ++ni)
        acc[mi][ni] = __builtin_amdgcn_mfma_f32_16x16x32_bf16(af[mi], bfr[ni], acc[mi][ni], 0, 0, 0);
  }
  const int b   = n0 >> (2 * lg);
  const int pgb = n0 & (HW - 1);
  const size_t obase = (size_t)b * R_TOTAL;
  const int aoff = D_AOFF[l];
  #pragma unroll
  for (int mi = 0; mi < 5; ++mi) {
    #pragma unroll
    for (int r = 0; r < 4; ++r) {
      int oc = mi * 16 + lq * 4 + r;
      if (oc < 75) {
        float bs = hbias[oc];
        size_t rr; int comp;
        if (oc < 15) { rr = (size_t)aoff + (size_t)oc * HW; comp = 0; }
        else { int o2 = oc - 15; rr = (size_t)aoff + (size_t)(o2 >> 2) * HW; comp = 1 + (o2 & 3); }
        #pragma unroll
        for (int ni = 0; ni < 2; ++ni) {
          int pg = pgb + wv * 32 + ni * 16 + lm;
          out[(obase + rr + pg) * 5 + comp] = acc[mi][ni][r] + bs;
        }
      }
    }
  }
}

// ---------------- launch -----------------------------------------------------------
extern "C" void kernel_launch(void* const* d_in, const int* in_sizes, int n_in,
                              void* d_out, int out_size, void* d_ws, size_t ws_size,
                              hipStream_t stream) {
  const float* f0     = (const float*)d_in[1];
  const float* f1     = (const float*)d_in[2];
  const float* f2     = (const float*)d_in[3];
  const float* f3     = (const float*)d_in[4];
  const float* f4     = (const float*)d_in[5];
  const float* gt     = (const float*)d_in[6];
  const float* conv_w = (const float*)d_in[7];
  const float* conv_b = (const float*)d_in[8];
  const float* cls_w  = (const float*)d_in[9];
  const float* cls_b  = (const float*)d_in[10];
  const float* box_w  = (const float*)d_in[11];
  const float* box_b  = (const float*)d_in[12];
  float* out = (float*)d_out;
  u8* wsb = (u8*)d_ws;

  u16*   wp    = (u16*)wsb;                      // 1,179,648 B
  u16*   Ft    = (u16*)(wsb + 1179648);          // 22,352,896 B
  u16*   tP    = (u16*)(wsb + 23532544);         // 22,347,776 B
  u16*   Wb    = (u16*)(wsb + 45880320);         // 40,960 B
  float* hbias = (float*)(wsb + 45921280);       // 320 B
  u64*   win   = (u64*)(wsb + 45921600);         // 512 B (64 x u64)
  u32*   done  = (u32*)(wsb + 45922112);         // 8 B

  (void)hipMemsetAsync(wsb + 45921600, 0, 520, stream);
  prep_label_kernel<<<5634, 256, 0, stream>>>(conv_w, wp, cls_w, cls_b, box_w, box_b,
                                              Wb, hbias, f0, f1, f2, f3, f4, Ft,
                                              gt, out, win, done);
  conv_mfma_kernel<<<1364, 256, 0, stream>>>(Ft, wp, conv_b, tP);
  head_mfma_kernel<<<682, 128, 0, stream>>>(tP, Wb, hbias, out);
}

// Round 8
// 246.394 us; speedup vs baseline: 1.8172x; 1.8172x over previous
//
#include <hip/hip_runtime.h>

typedef unsigned short u16;
typedef unsigned char  u8;
typedef unsigned int   u32;
typedef __bf16 bf16x8 __attribute__((ext_vector_type(8)));
typedef float  f32x4  __attribute__((ext_vector_type(4)));
typedef u16    u16x8  __attribute__((ext_vector_type(8)));
typedef u16    u16x4  __attribute__((ext_vector_type(4)));

// ---------------- constants ----------------
#define R_TOTAL 327360
#define LAB_OFF 3273600   // 2*R*5
#define MAT_OFF 3928320   // LAB_OFF + 2*R
#define NLBLK   1279      // label blocks per image (1279*256 >= R_TOTAL)

static __device__ const int    D_LOG2G[5] = {7, 6, 5, 4, 3};
static __device__ const size_t D_FTOFF[5] = {0, 8389120, 10486784, 11011584, 11143168};
static __device__ const int    D_TPOFF[5] = {0, 32768, 40960, 43008, 43520}; // pos units (x256 ch)
static __device__ const int    D_AOFF[5]  = {0, 245760, 307200, 322560, 326400};

static __device__ const float D_WH[15][2] = {
  {22.627416997969522f, 45.254833995939045f}, {32.f, 32.f},   {45.254833995939045f, 22.627416997969522f},
  {45.254833995939045f, 90.50966799187809f},  {64.f, 64.f},   {90.50966799187809f, 45.254833995939045f},
  {90.50966799187809f, 181.01933598375618f},  {128.f, 128.f}, {181.01933598375618f, 90.50966799187809f},
  {181.01933598375618f, 362.03867196751236f}, {256.f, 256.f}, {362.03867196751236f, 181.01933598375618f},
  {362.03867196751236f, 724.0773439350247f},  {512.f, 512.f}, {724.0773439350247f, 362.03867196751236f},
};

__device__ __forceinline__ u16 f2bf(float x) {          // RNE f32->bf16
  u32 u = __float_as_uint(x);
  u32 r = u + 0x7FFFu + ((u >> 16) & 1u);
  return (u16)(r >> 16);
}

__device__ __forceinline__ void glds16(const void* g, void* l) {
  __builtin_amdgcn_global_load_lds(
      (const __attribute__((address_space(1))) u32*)g,
      (__attribute__((address_space(3))) u32*)l, 16, 0, 0);
}

// ---------------- anchor decode (contract OFF) ----------------
__device__ inline void anchor_box(int r, float& x1, float& y1, float& x2, float& y2) {
  #pragma clang fp contract(off)
  int off, lg;
  if (r < 245760)      { off = 0;      lg = 7; }
  else if (r < 307200) { off = 245760; lg = 6; }
  else if (r < 322560) { off = 307200; lg = 5; }
  else if (r < 326400) { off = 322560; lg = 4; }
  else                 { off = 326400; lg = 3; }
  int rem  = r - off;
  int a    = rem >> (2 * lg);
  int rem2 = rem & ((1 << (2 * lg)) - 1);
  int i = rem2 >> lg;
  int j = rem2 & ((1 << lg) - 1);
  float stride = (float)(512 >> lg);
  float cx = (float)i * stride;
  float cy = (float)j * stride;
  float hw = D_WH[a][0] * 0.5f;
  float hh = D_WH[a][1] * 0.5f;
  x1 = cx - hw; y1 = cy - hh; x2 = cx + hw; y2 = cy + hh;
}

__device__ inline float iou_f(float ax1, float ay1, float ax2, float ay2,
                              float bx1, float by1, float bx2, float by2) {
  #pragma clang fp contract(off)
  float ltx = fmaxf(ax1, bx1), lty = fmaxf(ay1, by1);
  float rbx = fminf(ax2, bx2), rby = fminf(ay2, by2);
  float iw = fmaxf(rbx - ltx, 0.f);
  float ih = fmaxf(rby - lty, 0.f);
  float inter = iw * ih;
  float aa = (ax2 - ax1) * (ay2 - ay1);
  float ab = (bx2 - bx1) * (by2 - by1);
  return inter / (aa + ab - inter);
}

// ---------------- K1: packs + feature transpose + labels (fused, NO atomics) -------
// bid < 2304   : conv_w -> bf16 [ks][co][32] quarter-swizzled
// bid < 2384   : head weights -> Wb bf16 [80][256] + bias[80]
// bid < 3076   : features [b][ci][p] f32 -> [b][p][ci] bf16 (+zero halo row)
// else (2558)  : labels + matched + per-gt block partials (contention-free)
__global__ __launch_bounds__(256) void prep_label_kernel(
    const float* __restrict__ cw, u16* __restrict__ wp,
    const float* __restrict__ cls_w, const float* __restrict__ cls_b,
    const float* __restrict__ box_w, const float* __restrict__ box_b,
    u16* __restrict__ Wb, float* __restrict__ hbias,
    const float* __restrict__ f0, const float* __restrict__ f1,
    const float* __restrict__ f2, const float* __restrict__ f3,
    const float* __restrict__ f4, u16* __restrict__ Ft,
    const float* __restrict__ gt, float* __restrict__ out,
    float2* __restrict__ partial) {
  __shared__ union {
    float tile[64][65];
    struct {
      float gx[32][4];
      float sh[256][33];
      float2 red[32][8];
    } L;
  } sm;
  const int tid = threadIdx.x;
  if (blockIdx.x < 2304) {
    int idx = blockIdx.x * 256 + tid;   // < 589824
    int ks  = idx >> 13;
    int rem = idx & 8191;
    int co  = rem >> 5;
    int k   = rem & 31;
    int tap = ks >> 3;
    int cb  = ks & 7;
    float v = cw[co * 2304 + (cb * 32 + k) * 9 + tap];
    int qd = k >> 3, wi = k & 7;
    int dq = qd ^ ((co >> 1) & 3);
    wp[(size_t)ks * 8192 + co * 32 + dq * 8 + wi] = f2bf(v);
    return;
  }
  if (blockIdx.x < 2384) {
    int idx = (blockIdx.x - 2304) * 256 + tid;   // < 20480
    int row = idx >> 8, k = idx & 255;
    float v = (row < 15) ? cls_w[row * 256 + k] : (row < 75) ? box_w[(row - 15) * 256 + k] : 0.f;
    Wb[row * 256 + k] = f2bf(v);
    if (idx < 80) hbias[idx] = (idx < 15) ? cls_b[idx] : (idx < 75) ? box_b[idx - 15] : 0.f;
    return;
  }
  if (blockIdx.x < 3076) {
    int bid = blockIdx.x - 2384;    // < 692
    int l, base, nb1;
    if (bid < 514)      { l = 0; base = 0;   nb1 = 257; }
    else if (bid < 644) { l = 1; base = 514; nb1 = 65; }
    else if (bid < 678) { l = 2; base = 644; nb1 = 17; }
    else if (bid < 688) { l = 3; base = 678; nb1 = 5; }
    else                { l = 4; base = 688; nb1 = 2; }
    const int lg = D_LOG2G[l];
    const int HW = 1 << (2 * lg);
    int blk = bid - base;
    int b   = blk / nb1;
    int p0  = (blk - b * nb1) * 64;
    u16* dst = Ft + D_FTOFF[l];
    if (p0 >= HW) {      // zero halo row
      if (tid < 32) {
        u16x8 z = (u16x8)0;
        *(u16x8*)(dst + ((size_t)b * (HW + 1) + HW) * 256 + tid * 8) = z;
      }
      return;
    }
    const float* fsel = (l == 0) ? f0 : (l == 1) ? f1 : (l == 2) ? f2 : (l == 3) ? f3 : f4;
    const float* fb = fsel + (size_t)b * 256 * HW;
    for (int cg = 0; cg < 4; ++cg) {
      __syncthreads();
      #pragma unroll
      for (int i = 0; i < 16; ++i) {
        int idx = i * 256 + tid;
        int cl = idx >> 6, pp = idx & 63;
        sm.tile[cl][pp] = fb[(size_t)(cg * 64 + cl) * HW + p0 + pp];
      }
      __syncthreads();
      #pragma unroll
      for (int i = 0; i < 2; ++i) {
        int slot = i * 256 + tid;
        int pos = slot >> 3, ch = slot & 7;
        u16x8 v;
        #pragma unroll
        for (int j = 0; j < 8; ++j) v[j] = f2bf(sm.tile[ch * 8 + j][pos]);
        *(u16x8*)(dst + ((size_t)b * (HW + 1) + p0 + pos) * 256 + cg * 64 + ch * 8) = v;
      }
    }
    return;
  }
  // ---------------- label path (partial writes, no atomics) ----------------
  {
    #pragma clang fp contract(off)
    const int lb = blockIdx.x - 3076;          // < 2558
    const int b = (lb >= NLBLK) ? 1 : 0;
    const int lblk = lb - b * NLBLK;
    if (tid < 32) {
      const float* gp = gt + ((size_t)b * 32 + tid) * 4;
      float x = gp[0], y = gp[1], w = gp[2], h = gp[3];
      sm.L.gx[tid][0] = x; sm.L.gx[tid][1] = y;
      sm.L.gx[tid][2] = x + w; sm.L.gx[tid][3] = y + h;
    }
    __syncthreads();
    const int r = lblk * 256 + tid;
    const bool valid = (r < R_TOTAL);
    const int rv = valid ? r : 0;
    float ax1, ay1, ax2, ay2;
    anchor_box(rv, ax1, ay1, ax2, ay2);
    float best = -1e30f; int bi = 0;
    for (int n = 0; n < 32; ++n) {
      float v = iou_f(ax1, ay1, ax2, ay2, sm.L.gx[n][0], sm.L.gx[n][1], sm.L.gx[n][2], sm.L.gx[n][3]);
      sm.L.sh[tid][n] = valid ? v : -1e30f;
      if (v > best) { best = v; bi = n; }    // first-max (matches jnp.argmax)
    }
    if (valid) {
      float lab = (best < 0.3f) ? 0.f : ((best > 0.7f) ? 1.f : -1.f);
      out[LAB_OFF + (size_t)b * R_TOTAL + r] = lab;
      float4 m; m.x = sm.L.gx[bi][0]; m.y = sm.L.gx[bi][1];
      m.z = sm.L.gx[bi][2]; m.w = sm.L.gx[bi][3];
      *(float4*)&out[MAT_OFF + ((size_t)b * R_TOTAL + r) * 4] = m;
    }
    __syncthreads();
    // per-gt max over this block's 256 anchors
    const int n = tid & 31, gr = tid >> 5;
    float bv = -1e30f; int li = 0;
    #pragma unroll 4
    for (int a = 0; a < 32; ++a) {
      int la = gr * 32 + a;
      float v = sm.L.sh[la][n];
      if (v > bv) { bv = v; li = la; }       // ascending scan keeps first-max
    }
    sm.L.red[n][gr] = make_float2(bv, __int_as_float(li));
    __syncthreads();
    if (tid < 32) {
      float fv = -1e30f; int fi = 0;
      #pragma unroll
      for (int g2 = 0; g2 < 8; ++g2) {
        float2 pv = sm.L.red[tid][g2];
        int ii = __float_as_int(pv.y);
        if (pv.x > fv) { fv = pv.x; fi = ii; }   // g2 ascending => idx ascending
      }
      partial[(size_t)(b * 32 + tid) * NLBLK + lblk] =
          make_float2(fv, __int_as_float(lblk * 256 + fi));
    }
  }
}

// ---------------- K2: 3x3 conv via bf16 MFMA ---------------------------------------
// 1364 blocks (BM=128 co x BN=64 pos, BK=32), 256 thr / 4 waves
// (2co x 2pos wave grid, wave tile 64x32). 2-phase double-buffer.
__global__ __launch_bounds__(256) void conv_mfma_kernel(
    const u16* __restrict__ Ft, const u16* __restrict__ wp,
    const float* __restrict__ cb, u16* __restrict__ tP) {
  __shared__ __align__(16) u8 Asb[16384];   // 2 x 8KB (128 co x 32 ch)
  __shared__ __align__(16) u8 Bsb[8192];    // 2 x 4KB (64 pos x 32 ch)
  const int bid = blockIdx.x;
  int l, base;
  if (bid < 1024)      { l = 0; base = 0; }
  else if (bid < 1280) { l = 1; base = 1024; }
  else if (bid < 1344) { l = 2; base = 1280; }
  else if (bid < 1360) { l = 3; base = 1344; }
  else                 { l = 4; base = 1360; }
  const int lg = D_LOG2G[l];
  const int g = 1 << lg, HW = 1 << (2 * lg);
  const int lognt = 2 * lg - 5;            // log2(64-pos tiles over both images)
  const int blk = bid - base;
  const int ct = blk >> lognt;             // co half
  const int tile = blk & ((1 << lognt) - 1);
  const int n0 = tile << 6;                // flattened pos (tiles never cross images)
  const int co0 = ct << 7;
  const int tid = threadIdx.x;
  const int wv = tid >> 6, lane = tid & 63;
  const int wr = wv >> 1, wc = wv & 1;     // 2x2 wave grid (co x pos)
  const u16* FtL = Ft + D_FTOFF[l];
  const u8* wpb = (const u8*)wp;
  const int b_img = n0 >> (2 * lg);
  // staging: thread covers B row rB (pos n0+rB), quarter dq
  const int dq = tid & 3;
  const int rB = tid >> 2;                 // 0..63
  const int pgb = (n0 + rB) & (HW - 1);
  const int h0 = pgb >> lg, w0 = pgb & (g - 1);
  const int q0 = dq ^ ((rB >> 1) & 3);
  const u16* bimg = FtL + (size_t)b_img * (HW + 1) * 256;
  // fragment LDS byte offsets
  const int lm = lane & 15, lq = lane >> 4;
  int aoffs[4], boffs[2];
  #pragma unroll
  for (int mi = 0; mi < 4; ++mi) {
    int row = wr * 64 + mi * 16 + lm;
    aoffs[mi] = row * 64 + ((lq ^ ((row >> 1) & 3)) << 4);
  }
  #pragma unroll
  for (int ni = 0; ni < 2; ++ni) {
    int col = wc * 32 + ni * 16 + lm;
    boffs[ni] = col * 64 + ((lq ^ ((col >> 1) & 3)) << 4);
  }
  f32x4 acc[4][2];
  #pragma unroll
  for (int mi = 0; mi < 4; ++mi)
    #pragma unroll
    for (int ni = 0; ni < 2; ++ni) acc[mi][ni] = (f32x4)0.f;

  auto tap_src = [&](int tap) -> const u16* {
    const int dh = tap / 3 - 1, dw = tap % 3 - 1;
    int sh = h0 + dh, sw = w0 + dw;
    int rr = ((unsigned)sh < (unsigned)g && (unsigned)sw < (unsigned)g) ? (sh * g + sw) : HW;
    return bimg + (size_t)rr * 256 + q0 * 8;
  };
  auto STAGE = [&](int p, int ks, int cb8, const u16* s0) {
    glds16(s0 + cb8 * 32, Bsb + p * 4096 + wv * 1024);
    const u8* aK = wpb + (size_t)ks * 16384 + co0 * 64;
    glds16(aK + wv * 1024 + lane * 16,       Asb + p * 8192 + wv * 1024);
    glds16(aK + (4 + wv) * 1024 + lane * 16, Asb + p * 8192 + (4 + wv) * 1024);
  };

  const u16* cs0 = tap_src(0);
  int p = 0;
  STAGE(0, 0, 0, cs0);
  __syncthreads();

  for (int tap = 0; tap < 9; ++tap) {
    const u16* ns0 = (tap < 8) ? tap_src(tap + 1) : cs0;
    #pragma unroll
    for (int cb8 = 0; cb8 < 8; ++cb8) {
      if (!(tap == 8 && cb8 == 7)) {
        if (cb8 < 7) STAGE(p ^ 1, tap * 8 + cb8 + 1, cb8 + 1, cs0);
        else         STAGE(p ^ 1, (tap + 1) * 8, 0, ns0);
      }
      bf16x8 af[4], bfr[2];
      #pragma unroll
      for (int mi = 0; mi < 4; ++mi) af[mi] = *(const bf16x8*)(Asb + p * 8192 + aoffs[mi]);
      #pragma unroll
      for (int ni = 0; ni < 2; ++ni) bfr[ni] = *(const bf16x8*)(Bsb + p * 4096 + boffs[ni]);
      #pragma unroll
      for (int mi = 0; mi < 4; ++mi)
        #pragma unroll
        for (int ni = 0; ni < 2; ++ni)
          acc[mi][ni] = __builtin_amdgcn_mfma_f32_16x16x32_bf16(af[mi], bfr[ni], acc[mi][ni], 0, 0, 0);
      __syncthreads();
      p ^= 1;
    }
    cs0 = ns0;
  }
  // epilogue: bias + relu + bf16 store, position-major [p][co]
  u16* tPL = tP + ((size_t)D_TPOFF[l] + (size_t)b_img * HW) * 256;
  #pragma unroll
  for (int mi = 0; mi < 4; ++mi) {
    const int cob = co0 + wr * 64 + mi * 16 + lq * 4;
    const float4 bs = *(const float4*)&cb[cob];
    #pragma unroll
    for (int ni = 0; ni < 2; ++ni) {
      int pp = (n0 + wc * 32 + ni * 16 + lm) & (HW - 1);
      u16x4 v;
      v[0] = f2bf(fmaxf(acc[mi][ni][0] + bs.x, 0.f));
      v[1] = f2bf(fmaxf(acc[mi][ni][1] + bs.y, 0.f));
      v[2] = f2bf(fmaxf(acc[mi][ni][2] + bs.z, 0.f));
      v[3] = f2bf(fmaxf(acc[mi][ni][3] + bs.w, 0.f));
      *(u16x4*)&tPL[(size_t)pp * 256 + cob] = v;
    }
  }
}

// ---------------- K3: 1x1 heads via MFMA  (BM=80, BN=64, K=256) --------------------
__global__ __launch_bounds__(128) void head_mfma_kernel(
    const u16* __restrict__ tP, const u16* __restrict__ Wb,
    const float* __restrict__ hbias, float* __restrict__ out) {
  __shared__ __align__(16) u8 Bsb[32768];
  const int bid = blockIdx.x;
  int l, base;
  if (bid < 512)      { l = 0; base = 0; }
  else if (bid < 640) { l = 1; base = 512; }
  else if (bid < 672) { l = 2; base = 640; }
  else if (bid < 680) { l = 3; base = 672; }
  else                { l = 4; base = 680; }
  const int lg = D_LOG2G[l];
  const int HW = 1 << (2 * lg);
  const int blk = bid - base;
  const int n0 = blk << 6;             // global pos (2 images flattened)
  const int tid = threadIdx.x;
  const int wv = tid >> 6, lane = tid & 63;
  const int lm = lane & 15, lq = lane >> 4;
  const u16* src = tP + ((size_t)D_TPOFF[l] + n0) * 256;
  #pragma unroll
  for (int i = 0; i < 16; ++i) {
    int c = wv + i * 2;
    int slot = c * 64 + lane;
    int pos = slot >> 5, sp = slot & 31;
    glds16(src + (size_t)pos * 256 + ((sp ^ (pos & 7)) << 3), Bsb + c * 1024);
  }
  __syncthreads();
  f32x4 acc[5][2];
  #pragma unroll
  for (int mi = 0; mi < 5; ++mi) { acc[mi][0] = (f32x4)0.f; acc[mi][1] = (f32x4)0.f; }
  for (int kb = 0; kb < 8; ++kb) {
    bf16x8 af[5], bfr[2];
    #pragma unroll
    for (int mi = 0; mi < 5; ++mi)
      af[mi] = *(const bf16x8*)&Wb[(mi * 16 + lm) * 256 + kb * 32 + lq * 8];
    #pragma unroll
    for (int ni = 0; ni < 2; ++ni) {
      int p_ = wv * 32 + ni * 16 + lm;
      bfr[ni] = *(const bf16x8*)(Bsb + p_ * 512 + (((kb * 4 + lq) ^ (p_ & 7)) << 4));
    }
    #pragma unroll
    for (int mi = 0; mi < 5; ++mi)
      #pragma unroll
      for (int ni = 0; ni < 2; ++ni)
        acc[mi][ni] = __builtin_amdgcn_mfma_f32_16x16x32_bf16(af[mi], bfr[ni], acc[mi][ni], 0, 0, 0);
  }
  const int b   = n0 >> (2 * lg);
  const int pgb = n0 & (HW - 1);
  const size_t obase = (size_t)b * R_TOTAL;
  const int aoff = D_AOFF[l];
  #pragma unroll
  for (int mi = 0; mi < 5; ++mi) {
    #pragma unroll
    for (int r = 0; r < 4; ++r) {
      int oc = mi * 16 + lq * 4 + r;
      if (oc < 75) {
        float bs = hbias[oc];
        size_t rr; int comp;
        if (oc < 15) { rr = (size_t)aoff + (size_t)oc * HW; comp = 0; }
        else { int o2 = oc - 15; rr = (size_t)aoff + (size_t)(o2 >> 2) * HW; comp = 1 + (o2 & 3); }
        #pragma unroll
        for (int ni = 0; ni < 2; ++ni) {
          int pg = pgb + wv * 32 + ni * 16 + lm;
          out[(obase + rr + pg) * 5 + comp] = acc[mi][ni][r] + bs;
        }
      }
    }
  }
}

// ---------------- K4: finalize forced-positive labels ------------------------------
__global__ __launch_bounds__(256) void argmax_final2_kernel(
    const float* __restrict__ gt, const float2* __restrict__ partial,
    float* __restrict__ out) {
  #pragma clang fp contract(off)
  __shared__ float sv[256];
  __shared__ int   si[256];
  const int b = blockIdx.x >> 5, n = blockIdx.x & 31;
  const float2* pp = partial + (size_t)(b * 32 + n) * NLBLK;
  const int tid = threadIdx.x;
  float bv = -1e30f; int bi = 0x7fffffff;
  for (int i = tid; i < NLBLK; i += 256) {
    float2 pv = pp[i]; int ii = __float_as_int(pv.y);
    if (pv.x > bv || (pv.x == bv && ii < bi)) { bv = pv.x; bi = ii; }
  }
  sv[tid] = bv; si[tid] = bi;
  __syncthreads();
  for (int s = 128; s > 0; s >>= 1) {
    if (tid < s) {
      float v2 = sv[tid + s]; int i2 = si[tid + s];
      if (v2 > sv[tid] || (v2 == sv[tid] && i2 < si[tid])) { sv[tid] = v2; si[tid] = i2; }
    }
    __syncthreads();
  }
  if (tid == 0) {
    int banch = si[0];
    float ax1, ay1, ax2, ay2;
    anchor_box(banch, ax1, ay1, ax2, ay2);
    float score = -1e30f;
    for (int n2 = 0; n2 < 32; ++n2) {
      const float* gp = gt + ((size_t)b * 32 + n2) * 4;
      float v = iou_f(ax1, ay1, ax2, ay2, gp[0], gp[1], gp[0] + gp[2], gp[1] + gp[3]);
      score = fmaxf(score, v);
    }
    out[LAB_OFF + (size_t)b * R_TOTAL + banch] = (score < 0.3f) ? 0.f : 1.f;
  }
}

// ---------------- launch -----------------------------------------------------------
extern "C" void kernel_launch(void* const* d_in, const int* in_sizes, int n_in,
                              void* d_out, int out_size, void* d_ws, size_t ws_size,
                              hipStream_t stream) {
  const float* f0     = (const float*)d_in[1];
  const float* f1     = (const float*)d_in[2];
  const float* f2     = (const float*)d_in[3];
  const float* f3     = (const float*)d_in[4];
  const float* f4     = (const float*)d_in[5];
  const float* gt     = (const float*)d_in[6];
  const float* conv_w = (const float*)d_in[7];
  const float* conv_b = (const float*)d_in[8];
  const float* cls_w  = (const float*)d_in[9];
  const float* cls_b  = (const float*)d_in[10];
  const float* box_w  = (const float*)d_in[11];
  const float* box_b  = (const float*)d_in[12];
  float* out = (float*)d_out;
  u8* wsb = (u8*)d_ws;

  u16*    wp      = (u16*)wsb;                      // 1,179,648 B
  u16*    Ft      = (u16*)(wsb + 1179648);          // 22,352,896 B
  u16*    tP      = (u16*)(wsb + 23532544);         // 22,347,776 B
  u16*    Wb      = (u16*)(wsb + 45880320);         // 40,960 B
  float*  hbias   = (float*)(wsb + 45921280);       // 320 B
  float2* partial = (float2*)(wsb + 45921600);      // 2*32*1279*8 = 654,848 B

  prep_label_kernel<<<5634, 256, 0, stream>>>(conv_w, wp, cls_w, cls_b, box_w, box_b,
                                              Wb, hbias, f0, f1, f2, f3, f4, Ft,
                                              gt, out, partial);
  conv_mfma_kernel<<<1364, 256, 0, stream>>>(Ft, wp, conv_b, tP);
  head_mfma_kernel<<<682, 128, 0, stream>>>(tP, Wb, hbias, out);
  argmax_final2_kernel<<<64, 256, 0, stream>>>(gt, partial, out);
}